// Round 1
// baseline (1272.063 us; speedup 1.0000x reference)
//
#include <hip/hip_runtime.h>
#include <hip/hip_bf16.h>

#define BATCH 16
#define INP   128
#define OUP   128
#define HH    56
#define WW    56
#define HID   768
#define KC    64
#define NCHUNK 12      // HID / KC
#define TILE  8
#define HALO  10       // TILE + 2
#define NPIX  64       // TILE*TILE
#define NHALO 100      // HALO*HALO
#define EPSV  1e-5f

__launch_bounds__(256, 1)
__global__ void fused_ir(const float* __restrict__ x,
                         const float* __restrict__ w1,
                         const float* __restrict__ g1, const float* __restrict__ b1,
                         const float* __restrict__ m1, const float* __restrict__ v1,
                         const float* __restrict__ wdw,
                         const float* __restrict__ g2, const float* __restrict__ b2,
                         const float* __restrict__ m2, const float* __restrict__ v2,
                         const float* __restrict__ w2,
                         const float* __restrict__ g3, const float* __restrict__ b3,
                         const float* __restrict__ m3, const float* __restrict__ v3,
                         const int* __restrict__ mask,
                         float* __restrict__ out)
{
    // LDS budget ~130.5 KiB -> 1 block/CU on gfx950 (160 KiB LDS)
    __shared__ float xs[NHALO][INP];        // 51.2 KB  x halo tile, [pixel][chan]; GEMM reads are wave-uniform (broadcast)
    __shared__ float wbuf[KC][INP + 4];     // 33.8 KB  w1 chunk [64][128] (padded), reused as w2 chunk [128][64]
    __shared__ float h1s[NHALO][KC];        // 25.6 KB  expanded+BN1+relu6+md
    __shared__ float h2s[NPIX][KC + 4];     // 17.4 KB  dw+BN2+relu6+mf (pad 68 keeps float4 alignment, breaks stride-64 banks)
    __shared__ float wds[KC][9];            //  2.3 KB  depthwise taps
    __shared__ float s1v[KC], be1[KC], s2v[KC], be2[KC];
    __shared__ float s3v[OUP], be3[OUP];
    __shared__ float mfs[NPIX];             // mf at output pixels
    __shared__ float mds[NHALO];            // dilated mask at halo pixels (0 outside image => h1=0 pad for dw)
    __shared__ float mtmp[12][12];          // mf staging (+/-2 ring)

    const int tid = threadIdx.x;
    const int b   = blockIdx.y;
    const int ty  = blockIdx.x / 7, tx = blockIdx.x % 7;
    const int h0  = ty * TILE, w0 = tx * TILE;

    // ---- stage x halo tile (coalesced-ish runs of 10 along w) ----
    for (int idx = tid; idx < NHALO * INP; idx += 256) {
        int c = idx / NHALO;
        int p = idx - c * NHALO;
        int iy = p / HALO, ix = p - iy * HALO;
        int gy = h0 + iy - 1, gx = w0 + ix - 1;
        float v = 0.f;
        if (gy >= 0 && gy < HH && gx >= 0 && gx < WW)
            v = x[((b * INP + c) * HH + gy) * WW + gx];
        xs[p][c] = v;
    }
    // ---- stage mask 12x12 (0 outside image, matches reduce_window SAME pad) ----
    for (int idx = tid; idx < 144; idx += 256) {
        int iy = idx / 12, ix = idx - iy * 12;
        int gy = h0 + iy - 2, gx = w0 + ix - 2;
        float v = 0.f;
        if (gy >= 0 && gy < HH && gx >= 0 && gx < WW)
            v = (float)mask[(b * HH + gy) * WW + gx];
        mtmp[iy][ix] = v;
    }
    // ---- fold BN3 ----
    if (tid < OUP) {
        float s = g3[tid] * rsqrtf(v3[tid] + EPSV);
        s3v[tid] = s;
        be3[tid] = b3[tid] - m3[tid] * s;
    }
    __syncthreads();
    // ---- md at halo pixels; mf at output pixels ----
    for (int idx = tid; idx < NHALO; idx += 256) {
        int iy = idx / HALO, ix = idx - iy * HALO;
        int gy = h0 + iy - 1, gx = w0 + ix - 1;
        float mmax = 0.f;
        #pragma unroll
        for (int a2 = 0; a2 < 3; ++a2)
            #pragma unroll
            for (int c2 = 0; c2 < 3; ++c2)
                mmax = fmaxf(mmax, mtmp[iy + a2][ix + c2]);
        if (gy < 0 || gy >= HH || gx < 0 || gx >= WW) mmax = 0.f;  // dw zero-pad outside image
        mds[idx] = mmax;
    }
    if (tid < NPIX) {
        int ry = tid >> 3, rx = tid & 7;
        mfs[tid] = mtmp[ry + 2][rx + 2];
    }

    float acc[32];                 // project accumulators: thread owns pixel p=tid&63, oup block og*32..+31
    #pragma unroll
    for (int i = 0; i < 32; ++i) acc[i] = 0.f;

    const int lane_k = tid & 63;   // hidden-channel lane within chunk
    const int wgrp   = tid >> 6;   // wave index (uniform per wave)

    for (int ch = 0; ch < NCHUNK; ++ch) {
        const int k0 = ch * KC;
        __syncthreads();  // prev project done with wbuf/h2s; masks ready on first iter

        // stage w1 chunk [KC][INP]
        for (int idx = tid; idx < KC * INP; idx += 256) {
            int k = idx >> 7, c = idx & 127;
            wbuf[k][c] = w1[(k0 + k) * INP + c];
        }
        // dw taps + fold BN1/BN2 for this chunk
        for (int idx = tid; idx < KC * 9; idx += 256) {
            int k = idx / 9, t9 = idx - k * 9;
            wds[k][t9] = wdw[(k0 + k) * 9 + t9];
        }
        if (tid < KC) {
            int k = k0 + tid;
            float s = g1[k] * rsqrtf(v1[k] + EPSV);
            s1v[tid] = s; be1[tid] = b1[k] - m1[k] * s;
            float t = g2[k] * rsqrtf(v2[k] + EPSV);
            s2v[tid] = t; be2[tid] = b2[k] - m2[k] * t;
        }
        __syncthreads();

        // ---- expand GEMM: h1[p][lane_k], p = wgrp + 4i (p wave-uniform -> xs reads broadcast) ----
        {
            float a[25];
            #pragma unroll
            for (int i = 0; i < 25; ++i) a[i] = 0.f;
            for (int c4 = 0; c4 < INP / 4; ++c4) {
                const float4 wq = *(const float4*)&wbuf[lane_k][c4 * 4];
                #pragma unroll
                for (int i = 0; i < 25; ++i) {
                    const float4 xq = *(const float4*)&xs[wgrp + 4 * i][c4 * 4];
                    a[i] += wq.x * xq.x + wq.y * xq.y + wq.z * xq.z + wq.w * xq.w;
                }
            }
            const float s = s1v[lane_k], be = be1[lane_k];
            #pragma unroll
            for (int i = 0; i < 25; ++i) {
                int p = wgrp + 4 * i;
                h1s[p][lane_k] = fminf(fmaxf(a[i] * s + be, 0.f), 6.f) * mds[p];
            }
        }
        __syncthreads();

        // ---- depthwise 3x3 + BN2 + relu6 + mf (wave-uniform mf skip) ----
        {
            float wreg[9];
            #pragma unroll
            for (int t9 = 0; t9 < 9; ++t9) wreg[t9] = wds[lane_k][t9];
            const float s = s2v[lane_k], be = be2[lane_k];
            for (int i = 0; i < 16; ++i) {
                int p = wgrp * 16 + i;          // wave-uniform pixel
                int ry = p >> 3, rx = p & 7;
                float v = 0.f;
                if (mfs[p] != 0.f) {
                    #pragma unroll
                    for (int dy = 0; dy < 3; ++dy)
                        #pragma unroll
                        for (int dx = 0; dx < 3; ++dx)
                            v += h1s[(ry + dy) * HALO + rx + dx][lane_k] * wreg[dy * 3 + dx];
                    v = fminf(fmaxf(v * s + be, 0.f), 6.f);
                }
                h2s[p][lane_k] = v;
            }
        }
        // stage w2 chunk into wbuf as [OUP][KC] (wbuf reads finished before the barrier above)
        {
            float (*w2s)[KC] = (float (*)[KC])wbuf;
            for (int idx = tid; idx < OUP * KC; idx += 256) {
                int o = idx >> 6, kk = idx & 63;
                w2s[o][kk] = w2[o * HID + k0 + kk];
            }
        }
        __syncthreads();

        // ---- project accumulate: acc[oi] += h2[p][k0+kk] * w2[og*32+oi][k0+kk] ----
        {
            float (*w2s)[KC] = (float (*)[KC])wbuf;
            const int p = tid & 63, og = tid >> 6;
            for (int kq = 0; kq < KC / 4; ++kq) {
                const float4 hq = *(const float4*)&h2s[p][kq * 4];
                #pragma unroll
                for (int oi = 0; oi < 32; ++oi) {
                    const float4 wq = *(const float4*)&w2s[og * 32 + oi][kq * 4];  // wave-uniform -> broadcast
                    acc[oi] += hq.x * wq.x + hq.y * wq.y + hq.z * wq.z + hq.w * wq.w;
                }
            }
        }
    }

    // ---- epilogue: out = x + (BN3(proj)) * mf ----
    {
        const int p = tid & 63, og = tid >> 6;
        const int ry = p >> 3, rx = p & 7;
        const float mfv = mfs[p];
        const int hp = (ry + 1) * HALO + (rx + 1);
        const long base = (long)b * OUP * (HH * WW) + (long)(h0 + ry) * WW + (w0 + rx);
        #pragma unroll
        for (int oi = 0; oi < 32; ++oi) {
            int o = og * 32 + oi;
            float v = xs[hp][o] + (acc[oi] * s3v[o] + be3[o]) * mfv;
            out[base + (long)o * (HH * WW)] = v;
        }
    }
}

extern "C" void kernel_launch(void* const* d_in, const int* in_sizes, int n_in,
                              void* d_out, int out_size, void* d_ws, size_t ws_size,
                              hipStream_t stream) {
    const float* x   = (const float*)d_in[0];
    const float* w1  = (const float*)d_in[1];
    const float* g1  = (const float*)d_in[2];
    const float* b1  = (const float*)d_in[3];
    const float* m1  = (const float*)d_in[4];
    const float* v1  = (const float*)d_in[5];
    const float* wdw = (const float*)d_in[6];
    const float* g2  = (const float*)d_in[7];
    const float* b2  = (const float*)d_in[8];
    const float* m2  = (const float*)d_in[9];
    const float* v2  = (const float*)d_in[10];
    const float* w2  = (const float*)d_in[11];
    const float* g3  = (const float*)d_in[12];
    const float* b3  = (const float*)d_in[13];
    const float* m3  = (const float*)d_in[14];
    const float* v3  = (const float*)d_in[15];
    const int*  mask = (const int*)d_in[16];
    float* out = (float*)d_out;

    dim3 grid(49, BATCH);   // 7x7 tiles of 8x8 over 56x56, per batch
    fused_ir<<<grid, 256, 0, stream>>>(x, w1, g1, b1, m1, v1, wdw,
                                       g2, b2, m2, v2, w2, g3, b3, m3, v3,
                                       mask, out);
}

// Round 2
// 121.255 us; speedup vs baseline: 10.4908x; 10.4908x over previous
//
#include <hip/hip_runtime.h>
#include <hip/hip_bf16.h>

#define BATCH 16
#define INP   128
#define OUP   128
#define HH    56
#define WW    56
#define HID   768
#define KC    64          // hidden channels per chunk
#define NCHUNK 12
#define TILE  14
#define HALO  16          // TILE + 2
#define NHPX  256         // HALO*HALO
#define NIPX  196         // TILE*TILE
#define NPPX  208         // NIPX padded to 13*16
#define EPSV  1e-5f

typedef __attribute__((ext_vector_type(8))) short bf16x8;
typedef __attribute__((ext_vector_type(4))) float f32x4;

__device__ __forceinline__ unsigned short f2b(float f) {
    unsigned int u = __float_as_uint(f);
    unsigned int r = (u + 0x7FFFu + ((u >> 16) & 1u)) >> 16;   // RNE
    return (unsigned short)r;
}
__device__ __forceinline__ float blo(unsigned int u) { return __uint_as_float(u << 16); }
__device__ __forceinline__ float bhi(unsigned int u) { return __uint_as_float(u & 0xFFFF0000u); }

// LDS strides (elements)
#define XS_S   136        // 128 + 8 pad  (272B row, 16B aligned, banks spread)
#define H1_S   264        // 256 + 8 pad  (528B row)
#define H2_S   72         // 64 + 8 pad   (144B row)

__launch_bounds__(512, 2)
__global__ void fused_ir(const float* __restrict__ x,
                         const float* __restrict__ w1,
                         const float* __restrict__ g1, const float* __restrict__ b1,
                         const float* __restrict__ m1, const float* __restrict__ v1,
                         const float* __restrict__ wdw,
                         const float* __restrict__ g2, const float* __restrict__ b2,
                         const float* __restrict__ m2, const float* __restrict__ v2,
                         const float* __restrict__ w2,
                         const float* __restrict__ g3, const float* __restrict__ b3,
                         const float* __restrict__ m3, const float* __restrict__ v3,
                         const int* __restrict__ mask,
                         float* __restrict__ out)
{
    __shared__ unsigned short xs[NHPX * XS_S];    // 69632 B  x halo tile, bf16 [px][c]
    __shared__ unsigned short h1t[KC * H1_S];     // 33792 B  h1 chunk, bf16 [c][px]
    __shared__ unsigned short h2s[NPPX * H2_S];   // 29952 B  h2 chunk, bf16 [px][c]
    __shared__ float s1v[HID], be1[HID], s2v[HID], be2[HID];   // 12288 B
    __shared__ float s3v[OUP], be3[OUP];          // 1024 B
    __shared__ float mdv[NHPX];                   // 1024 B   dilated mask at halo px
    __shared__ float mfv_[NIPX];                  // 784 B    mask at inner px
    __shared__ float wds[KC * 9];                 // 2304 B   dw taps for chunk
    __shared__ float mtmp[18 * 18];               // 1296 B   mask staging

    const int t    = threadIdx.x;
    const int b    = blockIdx.y;
    const int tile = blockIdx.x;
    const int h0   = (tile >> 2) * TILE, w0 = (tile & 3) * TILE;
    const int lane = t & 63;
    const int w    = t >> 6;        // wave id 0..7
    const int g    = lane >> 4;     // k-group within fragment
    const int r16  = lane & 15;

    // ---------------- prologue ----------------
    // fold BN params (all chunks)
    for (int i = t; i < HID; i += 512) {
        float s = g1[i] * rsqrtf(v1[i] + EPSV);
        s1v[i] = s; be1[i] = b1[i] - m1[i] * s;
        float u = g2[i] * rsqrtf(v2[i] + EPSV);
        s2v[i] = u; be2[i] = b2[i] - m2[i] * u;
    }
    if (t < OUP) {
        float s = g3[t] * rsqrtf(v3[t] + EPSV);
        s3v[t] = s; be3[t] = b3[t] - m3[t] * s;
    }
    // mask 18x18 staging (0 outside image = reduce_window SAME pad)
    for (int i = t; i < 324; i += 512) {
        int iy = i / 18, ix = i - iy * 18;
        int gy = h0 + iy - 2, gx = w0 + ix - 2;
        float v = 0.f;
        if (gy >= 0 && gy < HH && gx >= 0 && gx < WW)
            v = (float)mask[(b * HH + gy) * WW + gx];
        mtmp[i] = v;
    }
    // zero h2s pad rows (px 196..207) once; never written again
    for (int i = t; i < (NPPX - NIPX) * H2_S; i += 512)
        h2s[NIPX * H2_S + i] = 0;
    // stage x halo -> bf16 LDS [px][c]
    for (int rep = 0; rep < 16; ++rep) {
        int id = t + rep * 512;                 // 8192 tasks: px (fast) x c4-group
        int px = id & 255, c0 = (id >> 8) * 4;
        int hy = px >> 4, hx = px & 15;
        int gy = h0 + hy - 1, gx = w0 + hx - 1;
        ushort4 u; u.x = 0; u.y = 0; u.z = 0; u.w = 0;
        if (gy >= 0 && gy < HH && gx >= 0 && gx < WW) {
            const float* xp = x + (((size_t)b * INP + c0) * HH + gy) * WW + gx;
            u.x = f2b(xp[0]);
            u.y = f2b(xp[(size_t)HH * WW]);
            u.z = f2b(xp[2 * (size_t)HH * WW]);
            u.w = f2b(xp[3 * (size_t)HH * WW]);
        }
        *(ushort4*)&xs[px * XS_S + c0] = u;
    }
    __syncthreads();
    // dilated mask at halo px; mask at inner px
    for (int i = t; i < NHPX; i += 512) {
        int hy = i >> 4, hx = i & 15;
        int gy = h0 + hy - 1, gx = w0 + hx - 1;
        float mm = 0.f;
        #pragma unroll
        for (int dy = 0; dy < 3; ++dy)
            #pragma unroll
            for (int dx = 0; dx < 3; ++dx)
                mm = fmaxf(mm, mtmp[(hy + dy) * 18 + hx + dx]);
        if (gy < 0 || gy >= HH || gx < 0 || gx >= WW) mm = 0.f;
        mdv[i] = mm;
    }
    for (int i = t; i < NIPX; i += 512) {
        int iy = i / 14, ix = i - iy * 14;
        mfv_[i] = mtmp[(iy + 2) * 18 + ix + 2];
    }
    __syncthreads();

    // project accumulators: wave w owns out-ch tile [w*16, w*16+16)
    f32x4 pacc[13];
    #pragma unroll
    for (int nt = 0; nt < 13; ++nt) { pacc[nt][0] = 0.f; pacc[nt][1] = 0.f; pacc[nt][2] = 0.f; pacc[nt][3] = 0.f; }

    const int mt = w & 3;          // expand m-tile (16 hidden ch)
    const int nhalf = w >> 2;      // expand n-half (8 tiles of 16 px)

    for (int ch = 0; ch < NCHUNK; ++ch) {
        const int k0 = ch * KC;

        // ---- phase E: expand MFMA (+ stage dw taps for this chunk) ----
        for (int i = t; i < KC * 9; i += 512)
            wds[i] = wdw[k0 * 9 + i];

        {
            bf16x8 af[4];
            #pragma unroll
            for (int ks = 0; ks < 4; ++ks) {
                const float* wp = w1 + (size_t)(k0 + mt * 16 + r16) * INP + ks * 32 + g * 8;
                float4 a0 = *(const float4*)wp;
                float4 a1 = *(const float4*)(wp + 4);
                bf16x8 v;
                v[0] = (short)f2b(a0.x); v[1] = (short)f2b(a0.y);
                v[2] = (short)f2b(a0.z); v[3] = (short)f2b(a0.w);
                v[4] = (short)f2b(a1.x); v[5] = (short)f2b(a1.y);
                v[6] = (short)f2b(a1.z); v[7] = (short)f2b(a1.w);
                af[ks] = v;
            }
            float s1r[4], b1r[4];
            #pragma unroll
            for (int i = 0; i < 4; ++i) {
                int c = k0 + mt * 16 + g * 4 + i;
                s1r[i] = s1v[c]; b1r[i] = be1[c];
            }
            #pragma unroll
            for (int j = 0; j < 8; ++j) {
                int nt = nhalf * 8 + j;
                int px = nt * 16 + r16;
                f32x4 acc; acc[0] = 0.f; acc[1] = 0.f; acc[2] = 0.f; acc[3] = 0.f;
                #pragma unroll
                for (int ks = 0; ks < 4; ++ks) {
                    bf16x8 bf = *(bf16x8*)&xs[px * XS_S + (4 * ks + g) * 8];
                    acc = __builtin_amdgcn_mfma_f32_16x16x32_bf16(af[ks], bf, acc, 0, 0, 0);
                }
                float mdp = mdv[px];
                #pragma unroll
                for (int i = 0; i < 4; ++i) {
                    float v = fminf(fmaxf(acc[i] * s1r[i] + b1r[i], 0.f), 6.f) * mdp;
                    h1t[(mt * 16 + g * 4 + i) * H1_S + px] = f2b(v);
                }
            }
        }
        __syncthreads();

        // ---- phase D: depthwise 3x3 + BN2 + relu6 + mf ----
        for (int rep = 0; rep < 2; ++rep) {
            int id = t + rep * 512;
            if (id < 896) {                      // 64 ch x 14 rows
                int c = id & 63, y = id >> 6;
                float rr[3][16];
                #pragma unroll
                for (int dy = 0; dy < 3; ++dy) {
                    const unsigned short* hp = &h1t[c * H1_S + (y + dy) * 16];
                    uint4 q0 = *(const uint4*)hp;
                    uint4 q1 = *(const uint4*)(hp + 8);
                    rr[dy][0] = blo(q0.x);  rr[dy][1] = bhi(q0.x);
                    rr[dy][2] = blo(q0.y);  rr[dy][3] = bhi(q0.y);
                    rr[dy][4] = blo(q0.z);  rr[dy][5] = bhi(q0.z);
                    rr[dy][6] = blo(q0.w);  rr[dy][7] = bhi(q0.w);
                    rr[dy][8] = blo(q1.x);  rr[dy][9] = bhi(q1.x);
                    rr[dy][10] = blo(q1.y); rr[dy][11] = bhi(q1.y);
                    rr[dy][12] = blo(q1.z); rr[dy][13] = bhi(q1.z);
                    rr[dy][14] = blo(q1.w); rr[dy][15] = bhi(q1.w);
                }
                float wt[9];
                #pragma unroll
                for (int tp = 0; tp < 9; ++tp) wt[tp] = wds[c * 9 + tp];
                float s2 = s2v[k0 + c], bb = be2[k0 + c];
                #pragma unroll
                for (int xx = 0; xx < 14; ++xx) {
                    float mv = mfv_[y * 14 + xx];     // uniform across wave (lanes = channels)
                    float v = 0.f;
                    if (mv != 0.f) {
                        float s = rr[0][xx] * wt[0] + rr[0][xx + 1] * wt[1] + rr[0][xx + 2] * wt[2]
                                + rr[1][xx] * wt[3] + rr[1][xx + 1] * wt[4] + rr[1][xx + 2] * wt[5]
                                + rr[2][xx] * wt[6] + rr[2][xx + 1] * wt[7] + rr[2][xx + 2] * wt[8];
                        v = fminf(fmaxf(s * s2 + bb, 0.f), 6.f) * mv;
                    }
                    h2s[(y * 14 + xx) * H2_S + c] = f2b(v);
                }
            }
        }
        __syncthreads();

        // ---- phase P: project MFMA accumulate ----
        {
            bf16x8 pf[2];
            #pragma unroll
            for (int ks = 0; ks < 2; ++ks) {
                const float* wp = w2 + (size_t)(w * 16 + r16) * HID + k0 + ks * 32 + g * 8;
                float4 a0 = *(const float4*)wp;
                float4 a1 = *(const float4*)(wp + 4);
                bf16x8 v;
                v[0] = (short)f2b(a0.x); v[1] = (short)f2b(a0.y);
                v[2] = (short)f2b(a0.z); v[3] = (short)f2b(a0.w);
                v[4] = (short)f2b(a1.x); v[5] = (short)f2b(a1.y);
                v[6] = (short)f2b(a1.z); v[7] = (short)f2b(a1.w);
                pf[ks] = v;
            }
            #pragma unroll
            for (int nt = 0; nt < 13; ++nt) {
                int px = nt * 16 + r16;
                #pragma unroll
                for (int ks = 0; ks < 2; ++ks) {
                    bf16x8 hb = *(bf16x8*)&h2s[px * H2_S + (4 * ks + g) * 8];
                    pacc[nt] = __builtin_amdgcn_mfma_f32_16x16x32_bf16(pf[ks], hb, pacc[nt], 0, 0, 0);
                }
            }
        }
        // no barrier: next E writes h1t (last read pre-barrier in D) and xs (read-only)
    }

    // ---------------- epilogue: BN3 * mf + residual ----------------
    {
        float s3r[4], b3r[4];
        #pragma unroll
        for (int i = 0; i < 4; ++i) {
            int o = w * 16 + g * 4 + i;
            s3r[i] = s3v[o]; b3r[i] = be3[o];
        }
        #pragma unroll
        for (int nt = 0; nt < 13; ++nt) {
            int ip = nt * 16 + r16;
            if (ip < NIPX) {
                int iy = ip / 14, ix = ip - iy * 14;
                int gy = h0 + iy, gx = w0 + ix;
                float mv = mfv_[ip];
                #pragma unroll
                for (int i = 0; i < 4; ++i) {
                    int o = w * 16 + g * 4 + i;
                    size_t off = (((size_t)b * OUP + o) * HH + gy) * WW + gx;
                    out[off] = x[off] + (pacc[nt][i] * s3r[i] + b3r[i]) * mv;
                }
            }
        }
    }
}

extern "C" void kernel_launch(void* const* d_in, const int* in_sizes, int n_in,
                              void* d_out, int out_size, void* d_ws, size_t ws_size,
                              hipStream_t stream) {
    (void)in_sizes; (void)n_in; (void)d_ws; (void)ws_size; (void)out_size;
    const float* x   = (const float*)d_in[0];
    const float* w1  = (const float*)d_in[1];
    const float* g1  = (const float*)d_in[2];
    const float* b1  = (const float*)d_in[3];
    const float* m1  = (const float*)d_in[4];
    const float* v1  = (const float*)d_in[5];
    const float* wdw = (const float*)d_in[6];
    const float* g2  = (const float*)d_in[7];
    const float* b2  = (const float*)d_in[8];
    const float* m2  = (const float*)d_in[9];
    const float* v2  = (const float*)d_in[10];
    const float* w2  = (const float*)d_in[11];
    const float* g3  = (const float*)d_in[12];
    const float* b3  = (const float*)d_in[13];
    const float* m3  = (const float*)d_in[14];
    const float* v3  = (const float*)d_in[15];
    const int*  mask = (const int*)d_in[16];
    float* out = (float*)d_out;

    dim3 grid(16, BATCH);   // 4x4 tiles of 14x14 over 56x56, per batch
    fused_ir<<<grid, 512, 0, stream>>>(x, w1, g1, b1, m1, v1, wdw,
                                       g2, b2, m2, v2, w2, g3, b3, m3, v3,
                                       mask, out);
}